// Round 15
// baseline (289.815 us; speedup 1.0000x reference)
//
#include <hip/hip_runtime.h>
#include <hip/hip_bf16.h>

typedef __attribute__((ext_vector_type(4))) float f32x4;
typedef __attribute__((ext_vector_type(8))) short s16x8;
typedef unsigned short u16;

#define B_   2
#define L_   2048
#define D_   768
#define H_   12
#define HD_  64
#define LN_  1536   // merged length: 512 unm + 1024 dst
#define HID_ 3072

__device__ __forceinline__ u16 f2bf(float f) {
    union { float f; unsigned u; } v; v.f = f;
    unsigned r = (v.u + 0x7FFFu + ((v.u >> 16) & 1u)) >> 16;
    return (u16)r;
}
__device__ __forceinline__ float bf2f(u16 v) {
    union { unsigned u; float f; } x; x.u = ((unsigned)v) << 16; return x.f;
}

__device__ __forceinline__ void gload_lds16(const void* g, void* l) {
    __builtin_amdgcn_global_load_lds((const __attribute__((address_space(1))) void*)g,
                                     (__attribute__((address_space(3))) void*)l, 16, 0, 0);
}

#define WAITV(n) asm volatile("s_waitcnt vmcnt(" #n ")" ::: "memory")

// ======= fused setup: LN1 (blocks 0..4095) | weight transposes (4096..11007) | wkm (11008..11199) =======
__global__ __launch_bounds__(256) void setup_fused(const float* __restrict__ x,
                                                   const float* __restrict__ ln1g,
                                                   const float* __restrict__ ln1b,
                                                   float* __restrict__ hf,
                                                   u16* __restrict__ hb,
                                                   const float* __restrict__ Wqkv,
                                                   const float* __restrict__ Wproj,
                                                   const float* __restrict__ W1,
                                                   const float* __restrict__ W2,
                                                   u16* __restrict__ WqkvT, u16* __restrict__ WprojT,
                                                   u16* __restrict__ W1T, u16* __restrict__ W2T,
                                                   const float* __restrict__ bqkv,
                                                   float* __restrict__ wkmT, float* __restrict__ bkm) {
    __shared__ float sm[8];
    __shared__ float tile[32][33];
    int bid = blockIdx.x;
    int t = threadIdx.x;
    if (bid < 4096) {
        // ---- LN1 ----
        int row = bid;
        const float* xr = x + (size_t)row * D_;
        float4 v = make_float4(0.f, 0.f, 0.f, 0.f);
        float s = 0.f, s2 = 0.f;
        if (t < 192) {
            v = ((const float4*)xr)[t];
            s = v.x + v.y + v.z + v.w;
            s2 = v.x * v.x + v.y * v.y + v.z * v.z + v.w * v.w;
        }
        for (int o = 32; o; o >>= 1) { s += __shfl_down(s, o); s2 += __shfl_down(s2, o); }
        int wv = t >> 6, ln = t & 63;
        if (ln == 0) { sm[wv] = s; sm[4 + wv] = s2; }
        __syncthreads();
        if (t == 0) { sm[0] = sm[0] + sm[1] + sm[2] + sm[3]; sm[4] = sm[4] + sm[5] + sm[6] + sm[7]; }
        __syncthreads();
        float mu = sm[0] * (1.f / D_);
        float var = sm[4] * (1.f / D_) - mu * mu;
        float rs = rsqrtf(var + 1e-5f);
        if (t < 192) {
            float4 gg = ((const float4*)ln1g)[t], bv = ((const float4*)ln1b)[t];
            float4 o;
            o.x = (v.x - mu) * rs * gg.x + bv.x;
            o.y = (v.y - mu) * rs * gg.y + bv.y;
            o.z = (v.z - mu) * rs * gg.z + bv.z;
            o.w = (v.w - mu) * rs * gg.w + bv.w;
            ((float4*)(hf + (size_t)row * D_))[t] = o;
            ushort4 u;
            u.x = f2bf(o.x); u.y = f2bf(o.y); u.z = f2bf(o.z); u.w = f2bf(o.w);
            ((ushort4*)(hb + (size_t)row * D_))[t] = u;
        }
        return;
    }
    if (bid < 11008) {
        // ---- weight transpose+cast ----
        int lb = bid - 4096;
        const float* in; u16* out; int R, C, gx, local;
        if (lb < 1728)      { in = Wqkv;  out = WqkvT;  R = D_;   C = 3 * D_; gx = 72; local = lb; }
        else if (lb < 2304) { in = Wproj; out = WprojT; R = D_;   C = D_;     gx = 24; local = lb - 1728; }
        else if (lb < 4608) { in = W1;    out = W1T;    R = D_;   C = HID_;   gx = 96; local = lb - 2304; }
        else                { in = W2;    out = W2T;    R = HID_; C = D_;     gx = 24; local = lb - 4608; }
        int c0 = (local % gx) * 32, r0 = (local / gx) * 32;
        int tx = t & 31, ty = t >> 5;   // 32 x 8
        for (int i = 0; i < 32; i += 8)
            tile[ty + i][tx] = in[(size_t)(r0 + ty + i) * C + c0 + tx];
        __syncthreads();
        for (int i = 0; i < 32; i += 8)
            out[(size_t)(c0 + ty + i) * R + r0 + tx] = f2bf(tile[tx][ty + i]);
        return;
    }
    {
        // ---- build mean-of-head-block Wk (transposed) + bk ----
        int idx = (bid - 11008) * 256 + t;
        if (idx < D_ * HD_) {
            int k = idx >> 6, c = idx & 63;
            float s = 0.f;
            #pragma unroll
            for (int hh = 0; hh < H_; ++hh) s += Wqkv[(size_t)k * (3 * D_) + D_ + hh * HD_ + c];
            wkmT[(size_t)c * D_ + k] = s * (1.f / H_);
        }
        if (idx < HD_) {
            float s = 0.f;
            #pragma unroll
            for (int hh = 0; hh < H_; ++hh) s += bqkv[D_ + hh * HD_ + idx];
            bkm[idx] = s * (1.f / H_);
        }
    }
}

// ---------------- fused merge_div + LayerNorm2 ----------------
__global__ __launch_bounds__(256) void ln_div_kernel(float* __restrict__ x_new,
                                                     const float* __restrict__ s_new,
                                                     const float* __restrict__ g,
                                                     const float* __restrict__ bb,
                                                     u16* __restrict__ hb) {
    __shared__ float sm[8];
    int row = blockIdx.x;
    float inv = 1.f / (s_new[row] + 1e-8f);
    float* xr = x_new + (size_t)row * D_;
    int t = threadIdx.x;
    float4 v = make_float4(0.f, 0.f, 0.f, 0.f);
    float s = 0.f, s2 = 0.f;
    if (t < 192) {
        v = ((float4*)xr)[t];
        v.x *= inv; v.y *= inv; v.z *= inv; v.w *= inv;
        ((float4*)xr)[t] = v;
        s = v.x + v.y + v.z + v.w;
        s2 = v.x * v.x + v.y * v.y + v.z * v.z + v.w * v.w;
    }
    for (int o = 32; o; o >>= 1) { s += __shfl_down(s, o); s2 += __shfl_down(s2, o); }
    int wv = t >> 6, ln = t & 63;
    if (ln == 0) { sm[wv] = s; sm[4 + wv] = s2; }
    __syncthreads();
    if (t == 0) { sm[0] = sm[0] + sm[1] + sm[2] + sm[3]; sm[4] = sm[4] + sm[5] + sm[6] + sm[7]; }
    __syncthreads();
    float mu = sm[0] * (1.f / D_);
    float var = sm[4] * (1.f / D_) - mu * mu;
    float rs = rsqrtf(var + 1e-5f);
    if (t < 192) {
        float4 gg = ((const float4*)g)[t], bv = ((const float4*)bb)[t];
        ushort4 u;
        u.x = f2bf((v.x - mu) * rs * gg.x + bv.x);
        u.y = f2bf((v.y - mu) * rs * gg.y + bv.y);
        u.z = f2bf((v.z - mu) * rs * gg.z + bv.z);
        u.w = f2bf((v.w - mu) * rs * gg.w + bv.w);
        ((ushort4*)(hb + (size_t)row * D_))[t] = u;
    }
}

// ---------------- split-K bf16 partial reduce: out = sum(parts) + bias + resid ----------------
__global__ __launch_bounds__(256) void reduce_splitk(const u16* __restrict__ parts,
                                                     const float* __restrict__ bias,
                                                     const float* __restrict__ resid,
                                                     float* __restrict__ out,
                                                     int nparts, int MN, int N4, int total4) {
    int i = blockIdx.x * 256 + threadIdx.x;
    if (i >= total4) return;
    float4 s = ((const float4*)bias)[i % N4];
    if (resid) {
        float4 r = ((const float4*)resid)[i];
        s.x += r.x; s.y += r.y; s.z += r.z; s.w += r.w;
    }
    for (int p = 0; p < nparts; ++p) {
        ushort4 v = *(const ushort4*)(parts + (size_t)p * MN + 4 * (size_t)i);
        s.x += bf2f(v.x); s.y += bf2f(v.y); s.z += bf2f(v.z); s.w += bf2f(v.w);
    }
    ((float4*)out)[i] = s;
}

// ========== unified 128x192 GEMM, 512 thr / 8 waves, 2 blocks/CU (r12 config) ==========
#define BM2 128
#define BN2 192
#define BK2 64
__global__ __launch_bounds__(512, 4) void gemm192(const u16* __restrict__ A, const u16* __restrict__ BT,
                                                  const float* __restrict__ bias,
                                                  u16* __restrict__ Cb,
                                                  u16* __restrict__ Vt,
                                                  int M, int N, int K, int flags) {
    __shared__ __align__(16) u16 As[2][BM2 * BK2];   // 32 KiB
    __shared__ __align__(16) u16 Bs[2][BN2 * BK2];   // 48 KiB
    int tid = threadIdx.x;
    int wave = tid >> 6, lane = tid & 63;
    int wr = wave >> 2, wc = wave & 3;
    int l15 = lane & 15, l4 = lane >> 4;
    int mBase = blockIdx.y * BM2, nBase = blockIdx.x * BN2;
    f32x4 acc[4][3] = {};
    int Ksplit = K / gridDim.z;
    int kt0 = (blockIdx.z * Ksplit) / BK2, kt1 = kt0 + Ksplit / BK2;
    int lrow = lane >> 3, lsl = lane & 7;

    auto stage = [&](int kt, int buf) {   // 5 loads/thread (2 A + 3 B)
        size_t koff = (size_t)kt * BK2;
        #pragma unroll
        for (int i = 0; i < 2; ++i) {
            int rbase = wave * 16 + i * 8;
            int row = rbase + lrow;
            int gc = lsl ^ (row & 7);
            gload_lds16(A + (size_t)(mBase + row) * K + koff + gc * 8, &As[buf][rbase * BK2]);
        }
        #pragma unroll
        for (int i = 0; i < 3; ++i) {
            int rbase = wave * 24 + i * 8;
            int row = rbase + lrow;
            int gc = lsl ^ (row & 7);
            gload_lds16(BT + (size_t)(nBase + row) * K + koff + gc * 8, &Bs[buf][rbase * BK2]);
        }
    };

    stage(kt0, 0);
    int cur = 0;
    for (int kt = kt0; kt < kt1; ++kt) {
        if (kt + 1 < kt1) {
            stage(kt + 1, cur ^ 1);
            WAITV(5);
        } else {
            WAITV(0);
        }
        __builtin_amdgcn_s_barrier();
        #pragma unroll
        for (int kk = 0; kk < 2; ++kk) {
            s16x8 af[4], bf[3];
            #pragma unroll
            for (int mi = 0; mi < 4; ++mi) {
                int row = wr * 64 + mi * 16 + l15;
                int ch = kk * 4 + l4;
                af[mi] = *(const s16x8*)&As[cur][row * BK2 + ((ch ^ (row & 7)) * 8)];
            }
            #pragma unroll
            for (int ni = 0; ni < 3; ++ni) {
                int row = wc * 48 + ni * 16 + l15;
                int ch = kk * 4 + l4;
                bf[ni] = *(const s16x8*)&Bs[cur][row * BK2 + ((ch ^ (row & 7)) * 8)];
            }
            __builtin_amdgcn_s_setprio(1);
            #pragma unroll
            for (int mi = 0; mi < 4; ++mi)
                #pragma unroll
                for (int ni = 0; ni < 3; ++ni)
                    acc[mi][ni] = __builtin_amdgcn_mfma_f32_16x16x32_bf16(af[mi], bf[ni], acc[mi][ni], 0, 0, 0);
            __builtin_amdgcn_s_setprio(0);
        }
        asm volatile("s_waitcnt lgkmcnt(0)" ::: "memory");
        __builtin_amdgcn_s_barrier();
        cur ^= 1;
    }

    if (flags & 4) {
        #pragma unroll
        for (int mi = 0; mi < 4; ++mi) {
            int r0 = mBase + wr * 64 + mi * 16 + l4 * 4;
            #pragma unroll
            for (int ni = 0; ni < 3; ++ni) {
                int c0 = nBase + wc * 48 + ni * 16;
                int col = c0 + l15;
                float bv = bias[col];
                if (c0 < 1536) {
                    #pragma unroll
                    for (int j = 0; j < 4; ++j)
                        Cb[(size_t)(r0 + j) * 1536 + col] = f2bf(acc[mi][ni][j] + bv);
                } else {
                    int hh = (col - 1536) >> 6, dd = (col - 1536) & 63;
                    int bb2 = r0 >> 11, tok = r0 & 2047;
                    ushort4 u;
                    u.x = f2bf(acc[mi][ni][0] + bv);
                    u.y = f2bf(acc[mi][ni][1] + bv);
                    u.z = f2bf(acc[mi][ni][2] + bv);
                    u.w = f2bf(acc[mi][ni][3] + bv);
                    *(ushort4*)&Vt[(((size_t)bb2 * H_ + hh) * HD_ + dd) * (size_t)L_ + tok] = u;
                }
            }
        }
        return;
    }
    if (gridDim.z > 1) {
        u16* dst = Cb + (size_t)blockIdx.z * M * N;
        #pragma unroll
        for (int mi = 0; mi < 4; ++mi)
            #pragma unroll
            for (int j = 0; j < 4; ++j) {
                int row = mBase + wr * 64 + mi * 16 + l4 * 4 + j;
                #pragma unroll
                for (int ni = 0; ni < 3; ++ni) {
                    int col = nBase + wc * 48 + ni * 16 + l15;
                    dst[(size_t)row * N + col] = f2bf(acc[mi][ni][j]);
                }
            }
        return;
    }
    #pragma unroll
    for (int mi = 0; mi < 4; ++mi) {
        #pragma unroll
        for (int j = 0; j < 4; ++j) {
            int row = mBase + wr * 64 + mi * 16 + l4 * 4 + j;
            #pragma unroll
            for (int ni = 0; ni < 3; ++ni) {
                int col = nBase + wc * 48 + ni * 16 + l15;
                float v = acc[mi][ni][j] + bias[col];
                if (flags & 1) v = 0.5f * v * (1.f + erff(v * 0.70710678118654752f));
                Cb[(size_t)row * N + col] = f2bf(v);
            }
        }
    }
}

// ---------------- k_merge + normalize + even/odd split (fp32) v2 ----------------
__global__ __launch_bounds__(256) void kmerge_kn(const float* __restrict__ hf, const float* __restrict__ wkmT,
                                                 const float* __restrict__ bkm,
                                                 float* __restrict__ aset, float* __restrict__ bset) {
    __shared__ __align__(16) float hfs[16][768];   // 48 KB
    int t = threadIdx.x, wave = t >> 6, lane = t & 63;
    int m0 = blockIdx.x * 16;
    for (int i = t; i < 16 * 192; i += 256) {
        int r = i / 192, c = i % 192;
        ((float4*)hfs[r])[c] = ((const float4*)(hf + (size_t)(m0 + r) * D_))[c];
    }
    __syncthreads();
    int r0 = wave * 4;
    float acc0 = 0.f, acc1 = 0.f, acc2 = 0.f, acc3 = 0.f;
    const float4* wrow = (const float4*)(wkmT + (size_t)lane * D_);
    #pragma unroll 4
    for (int k4 = 0; k4 < 192; ++k4) {
        float4 w = wrow[k4];
        float4 h0 = ((const float4*)hfs[r0 + 0])[k4];
        float4 h1 = ((const float4*)hfs[r0 + 1])[k4];
        float4 h2 = ((const float4*)hfs[r0 + 2])[k4];
        float4 h3 = ((const float4*)hfs[r0 + 3])[k4];
        acc0 = fmaf(h0.x, w.x, acc0); acc0 = fmaf(h0.y, w.y, acc0);
        acc0 = fmaf(h0.z, w.z, acc0); acc0 = fmaf(h0.w, w.w, acc0);
        acc1 = fmaf(h1.x, w.x, acc1); acc1 = fmaf(h1.y, w.y, acc1);
        acc1 = fmaf(h1.z, w.z, acc1); acc1 = fmaf(h1.w, w.w, acc1);
        acc2 = fmaf(h2.x, w.x, acc2); acc2 = fmaf(h2.y, w.y, acc2);
        acc2 = fmaf(h2.z, w.z, acc2); acc2 = fmaf(h2.w, w.w, acc2);
        acc3 = fmaf(h3.x, w.x, acc3); acc3 = fmaf(h3.y, w.y, acc3);
        acc3 = fmaf(h3.z, w.z, acc3); acc3 = fmaf(h3.w, w.w, acc3);
    }
    float accs[4] = {acc0, acc1, acc2, acc3};
    #pragma unroll
    for (int r = 0; r < 4; ++r) {
        float v = accs[r] + bkm[lane];
        float n2 = v * v;
        for (int o = 32; o; o >>= 1) n2 += __shfl_xor(n2, o);
        float kn = v / (sqrtf(n2) + 1e-8f);
        int m = m0 + r0 + r;
        int bb = m >> 11, l = m & 2047;
        float* dp = (l & 1) ? bset : aset;
        dp[((size_t)bb * 1024 + (l >> 1)) * 64 + lane] = kn;
    }
}

// ---------------- ToMe scores: rowwise max+argmax over 1024 cols ----------------
__global__ __launch_bounds__(256) void tome_scores(const float* __restrict__ aset, const float* __restrict__ bset,
                                                   float* __restrict__ node_max, int* __restrict__ node_idx) {
    __shared__ float aves[4][64];
    __shared__ unsigned long long wmax[4][4];
    int b = blockIdx.y;
    int a0 = blockIdx.x * 4;
    int t = threadIdx.x;
    { int r = t >> 6, d = t & 63; aves[r][d] = aset[((size_t)b * 1024 + a0 + r) * 64 + d]; }
    __syncthreads();
    unsigned long long best[4] = {0ull, 0ull, 0ull, 0ull};
    for (int c = t; c < 1024; c += 256) {
        const float4* brow = (const float4*)(bset + ((size_t)b * 1024 + c) * 64);
        float dot[4] = {0.f, 0.f, 0.f, 0.f};
        #pragma unroll
        for (int i = 0; i < 16; ++i) {
            float4 bv = brow[i];
            #pragma unroll
            for (int r = 0; r < 4; ++r) {
                dot[r] = fmaf(aves[r][4 * i + 0], bv.x, dot[r]);
                dot[r] = fmaf(aves[r][4 * i + 1], bv.y, dot[r]);
                dot[r] = fmaf(aves[r][4 * i + 2], bv.z, dot[r]);
                dot[r] = fmaf(aves[r][4 * i + 3], bv.w, dot[r]);
            }
        }
        #pragma unroll
        for (int r = 0; r < 4; ++r) {
            unsigned bits = __float_as_uint(dot[r]);
            unsigned u = (bits & 0x80000000u) ? ~bits : (bits | 0x80000000u);
            unsigned long long key = ((unsigned long long)u << 32) | (unsigned)(0xFFFFFFFFu - (unsigned)c);
            best[r] = best[r] > key ? best[r] : key;
        }
    }
    int wv = t >> 6, ln = t & 63;
    #pragma unroll
    for (int r = 0; r < 4; ++r) {
        unsigned long long v = best[r];
        for (int o = 32; o; o >>= 1) {
            unsigned long long w = __shfl_xor(v, o);
            v = v > w ? v : w;
        }
        if (ln == 0) wmax[r][wv] = v;
    }
    __syncthreads();
    if (t == 0) {
        for (int r = 0; r < 4; ++r) {
            int a = a0 + r;
            unsigned long long m = wmax[r][0];
            for (int w = 1; w < 4; ++w) m = m > wmax[r][w] ? m : wmax[r][w];
            float val; int idx;
            if (a == 0) { val = -INFINITY; idx = 0; }
            else {
                unsigned u = (unsigned)(m >> 32);
                unsigned bits = (u & 0x80000000u) ? (u ^ 0x80000000u) : ~u;
                val = __uint_as_float(bits);
                idx = (int)(0xFFFFFFFFu - (unsigned)(m & 0xFFFFFFFFu));
            }
            node_max[b * 1024 + a] = val;
            node_idx[b * 1024 + a] = idx;
        }
    }
}

// ====== attention (blocks 0..383, 128 queries each) + fused rank-select sort (blocks 384..385) ======
__global__ __launch_bounds__(512) void attn_mfma(const u16* __restrict__ qkb,
                                                 const u16* __restrict__ vtb,
                                                 const float* __restrict__ ts,
                                                 u16* __restrict__ ctx,
                                                 const float* __restrict__ node_max,
                                                 const int* __restrict__ node_idx,
                                                 int* __restrict__ src_idx, int* __restrict__ dst_idx,
                                                 int* __restrict__ unm_idx) {
    __shared__ __align__(16) u16 Ks[192 * 64];      // 24 KB
    __shared__ __align__(16) u16 Vt[64][200];       // 25.6 KB
    __shared__ float lts[192];
    __shared__ __align__(16) u16 Pw[8][16 * 40];    // 10 KB
    __shared__ unsigned long long skeys[1024];      // 8 KB (sort path)
    __shared__ int sranks[1024];                    // 4 KB (sort path)
    int bid = blockIdx.x;
    int tid = threadIdx.x;

    if (bid >= 384) {
        // ---- exact rank-select argsort (2 blocks, 512 thr, 2 elems/thread) ----
        int b = bid - 384;
        int rk[2];
        #pragma unroll
        for (int e = 0; e < 2; ++e) {
            int i = tid + e * 512;
            float v = node_max[b * 1024 + i];
            unsigned bits = __float_as_uint(v);
            unsigned u = (bits & 0x80000000u) ? ~bits : (bits | 0x80000000u);
            skeys[i] = ((unsigned long long)(~u) << 32) | (unsigned)i;
        }
        __syncthreads();
        #pragma unroll
        for (int e = 0; e < 2; ++e) {
            int i = tid + e * 512;
            unsigned long long key = skeys[i];
            int rank = 0;
            #pragma unroll 8
            for (int j = 0; j < 1024; ++j) rank += (skeys[j] < key) ? 1 : 0;
            rk[e] = rank;
            if (rank < 512) {
                src_idx[b * 512 + rank] = i;
                dst_idx[b * 512 + rank] = node_idx[b * 1024 + i];
            }
            sranks[i] = rank;
        }
        __syncthreads();
        #pragma unroll
        for (int e = 0; e < 2; ++e) {
            int i = tid + e * 512;
            if (rk[e] >= 512) {
                int slot = 0;
                #pragma unroll 8
                for (int j = 0; j < 1024; ++j) slot += (j < i && sranks[j] >= 512) ? 1 : 0;
                unm_idx[b * 512 + slot] = i;
            }
        }
        return;
    }

    // ---- attention ----
    int qt = bid & 15, h = (bid >> 4) % H_, b = bid / (16 * H_);
    int wave = tid >> 6, lane = tid & 63;
    int l15 = lane & 15, l4 = lane >> 4;
    int qbase = qt * 128 + wave * 16;
    int jbase0 = qt * 128 - 128;

    s16x8 qaf[2];
    {
        const u16* qp = qkb + (size_t)(b * L_ + qbase + l15) * 1536 + h * HD_;
        qaf[0] = *(const s16x8*)(qp + l4 * 8);
        qaf[1] = *(const s16x8*)(qp + 32 + l4 * 8);
    }
    f32x4 oacc[4] = {};
    float sums[4] = {0.f, 0.f, 0.f, 0.f};
    const u16* vbase = vtb + (size_t)(b * H_ + h) * HD_ * L_;

    for (int half = 0; half < 2; ++half) {
        int jbase = jbase0 + half * 192;
        __syncthreads();
        #pragma unroll
        for (int i = 0; i < 3; ++i) {
            int rbase = (wave * 3 + i) * 8;
            int row = rbase + (lane >> 3);
            int gc = (lane & 7) ^ (row & 7);
            int jc = min(max(jbase + row, 0), L_ - 1);
            gload_lds16(qkb + (size_t)(b * L_ + jc) * 1536 + 768 + h * HD_ + gc * 8, &Ks[rbase * 64]);
        }
        #pragma unroll
        for (int i = 0; i < 3; ++i) {
            int c = tid + 512 * i;          // 0..1535
            int d = c / 24, ch = c % 24;
            int tok0 = min(max(jbase + ch * 8, 0), L_ - 8);
            s16x8 v = *(const s16x8*)(vbase + (size_t)d * L_ + tok0);
            *(s16x8*)&Vt[d][ch * 8] = v;
        }
        if (tid < 192) {
            int jc = min(max(jbase + tid, 0), L_ - 1);
            lts[tid] = __logf(fmaxf(ts[b * L_ + jc], 1e-8f));
        }
        __syncthreads();
        #pragma unroll
        for (int kb = 0; kb < 6; ++kb) {
            #pragma unroll
            for (int f = 0; f < 2; ++f) {
                int kf16 = kb * 32 + f * 16;
                f32x4 s = {};
                #pragma unroll
                for (int c = 0; c < 2; ++c) {
                    int row = kf16 + l15;
                    int ch = (c * 4 + l4) ^ (row & 7);
                    s16x8 kf = *(const s16x8*)&Ks[row * 64 + ch * 8];
                    s = __builtin_amdgcn_mfma_f32_16x16x32_bf16(qaf[c], kf, s, 0, 0, 0);
                }
                int j = jbase + kf16 + l15;
                float lt = lts[kf16 + l15];
                #pragma unroll
                for (int jj = 0; jj < 4; ++jj) {
                    int q = qbase + l4 * 4 + jj;
                    int d = j - q;
                    bool ok = (j >= 0) && (j < L_) && (d >= -128) && (d <= 128);
                    float p = ok ? __expf(s[jj] * 0.125f + lt) : 0.f;
                    sums[jj] += p;
                    Pw[wave][(l4 * 4 + jj) * 40 + f * 16 + l15] = f2bf(p);
                }
            }
            asm volatile("s_waitcnt lgkmcnt(0)" ::: "memory");
            s16x8 paf = *(const s16x8*)&Pw[wave][l15 * 40 + l4 * 8];
            #pragma unroll
            for (int df = 0; df < 4; ++df) {
                s16x8 vbf = *(const s16x8*)&Vt[df * 16 + l15][kb * 32 + l4 * 8];
                oacc[df] = __builtin_amdgcn_mfma_f32_16x16x32_bf16(paf, vbf, oacc[df], 0, 0, 0);
            }
        }
    }
    #pragma unroll
    for (int jj = 0; jj < 4; ++jj) {
        float s = sums[jj];
        s += __shfl_xor(s, 1); s += __shfl_xor(s, 2);
        s += __shfl_xor(s, 4); s += __shfl_xor(s, 8);
        sums[jj] = 1.f / s;
    }
    #pragma unroll
    for (int jj = 0; jj < 4; ++jj) {
        int q = qbase + l4 * 4 + jj;
        u16* crow = ctx + (size_t)(b * L_ + q) * D_ + h * HD_;
        #pragma unroll
        for (int df = 0; df < 4; ++df)
            crow[df * 16 + l15] = f2bf(oacc[df][jj] * sums[jj]);
    }
}

// ---------------- merge kernels (fused proj split-K=3 bf16-partial reduce) ----------------
#define PMN (B_ * L_ * D_)   // one proj partial in elements

__device__ __forceinline__ float4 proj_row4(const u16* __restrict__ pp,
                                            const float* __restrict__ bproj,
                                            const float* __restrict__ x,
                                            int tok /*0..B*L-1*/, int t /*0..191*/) {
    size_t base = (size_t)tok * D_ + 4 * t;
    float4 s = ((const float4*)bproj)[t];
    float4 xv = ((const float4*)(x + (size_t)tok * D_))[t];
    s.x += xv.x; s.y += xv.y; s.z += xv.z; s.w += xv.w;
    #pragma unroll
    for (int p = 0; p < 3; ++p) {
        ushort4 v = *(const ushort4*)(pp + (size_t)p * PMN + base);
        s.x += bf2f(v.x); s.y += bf2f(v.y); s.z += bf2f(v.z); s.w += bf2f(v.w);
    }
    return s;
}

__global__ __launch_bounds__(256) void merge_init(const u16* __restrict__ pp,
                                                  const float* __restrict__ bproj,
                                                  const float* __restrict__ x,
                                                  const float* __restrict__ ts,
                                                  const int* __restrict__ unm_idx,
                                                  float* __restrict__ x_sum, float* __restrict__ s_new) {
    int row = blockIdx.x;
    int b = row / LN_, rl = row % LN_;
    int srcTok = (rl < 512) ? (2 * unm_idx[b * 512 + rl]) : (2 * (rl - 512) + 1);
    float tsv = ts[b * L_ + srcTok];
    int t = threadIdx.x;
    if (t < 192) {
        float4 v = proj_row4(pp, bproj, x, b * L_ + srcTok, t);
        v.x *= tsv; v.y *= tsv; v.z *= tsv; v.w *= tsv;
        ((float4*)(x_sum + (size_t)(b * LN_ + rl) * D_))[t] = v;
    }
    if (t == 0) s_new[b * LN_ + rl] = tsv;
}

__global__ __launch_bounds__(256) void merge_scatter(const u16* __restrict__ pp,
                                                     const float* __restrict__ bproj,
                                                     const float* __restrict__ x,
                                                     const float* __restrict__ ts,
                                                     const int* __restrict__ src_idx, const int* __restrict__ dst_idx,
                                                     float* __restrict__ x_sum, float* __restrict__ s_new) {
    int e = blockIdx.x;
    int b = e >> 9, el = e & 511;
    int s = src_idx[b * 512 + el];
    int dtok = dst_idx[b * 512 + el];
    int srcTok = 2 * s;
    float tsv = ts[b * L_ + srcTok];
    float* dst = x_sum + (size_t)(b * LN_ + 512 + dtok) * D_;
    int t = threadIdx.x;
    if (t < 192) {
        float4 v = proj_row4(pp, bproj, x, b * L_ + srcTok, t);
        atomicAdd(&dst[4 * t + 0], v.x * tsv);
        atomicAdd(&dst[4 * t + 1], v.y * tsv);
        atomicAdd(&dst[4 * t + 2], v.z * tsv);
        atomicAdd(&dst[4 * t + 3], v.w * tsv);
    }
    if (t == 0) atomicAdd(&s_new[b * LN_ + 512 + dtok], tsv);
}

extern "C" void kernel_launch(void* const* d_in, const int* in_sizes, int n_in,
                              void* d_out, int out_size, void* d_ws, size_t ws_size,
                              hipStream_t stream) {
    (void)in_sizes; (void)n_in; (void)out_size; (void)ws_size;
    const float* x     = (const float*)d_in[0];
    const float* ts    = (const float*)d_in[1];
    const float* ln1g  = (const float*)d_in[2];
    const float* ln1b  = (const float*)d_in[3];
    const float* ln2g  = (const float*)d_in[4];
    const float* ln2b  = (const float*)d_in[5];
    const float* Wqkv  = (const float*)d_in[6];
    const float* bqkv  = (const float*)d_in[7];
    const float* Wproj = (const float*)d_in[8];
    const float* bproj = (const float*)d_in[9];
    const float* W1    = (const float*)d_in[10];
    const float* b1    = (const float*)d_in[11];
    const float* W2    = (const float*)d_in[12];
    const float* b2    = (const float*)d_in[13];
    float* out = (float*)d_out;

    char* ws = (char*)d_ws;
    float* h_f32   = (float*)(ws + 0);            // 12582912
    u16*   h_bf16  = (u16*)(ws + 12582912);       // 6291456 (-> ctx)
    u16*   qkb     = (u16*)(ws + 18874368);       // 12582912 (dead after attn)
    u16*   vtb     = (u16*)(ws + 31457280);       // 6291456  (dead after attn)
    u16*   mid     = (u16*)(ws + 37748736);       // 18874368
    float* x_new   = (float*)(ws + 56623104);     // 9437184
    float* s_new   = (float*)(ws + 66060288);     // 12288
    u16*   h2      = (u16*)(ws + 66072576);       // 4718592
    u16*   WqkvT   = (u16*)(ws + 70791168);       // 3538944
    u16*   WprojT  = (u16*)(ws + 74330112);       // 1179648
    u16*   W1T     = (u16*)(ws + 75509760);       // 4718592
    u16*   W2T     = (u16*)(ws + 80228352);       // 4718592
    float* wkmT    = (float*)(ws + 84946944);     // 196608
    float* bkm     = (float*)(ws + 85143552);     // 256
    float* aset    = (float*)(ws + 85143808);     // 524288
    float* bset    = (float*)(ws + 85668096);     // 524288
    float* nmax    = (float*)(ws + 86192384);     // 8192
    int*   nidx    = (int*)(ws + 86200576);       // 8192
    int*   src_idx = (int*)(ws + 86208768);       // 4096
    int*   dst_idx = (int*)(ws + 86212864);       // 4096
    int*   unm_idx = (int*)(ws + 86216960);       // 4096
    u16*   ctx = h_bf16;
    u16*   ppartsB  = (u16*)(ws + 18874368);      // proj bf16 partials: 3 x 6291456 over qkb+vtb
    u16*   m2partsB = (u16*)(ws + 0);             // mlp2 bf16 partials: 4 x 4718592 over h_f32+ctx

    // 1. fused setup: LN1 + 4 weight transposes + wkm
    setup_fused<<<11200, 256, 0, stream>>>(x, ln1g, ln1b, h_f32, h_bf16,
                                           Wqkv, Wproj, W1, W2, WqkvT, WprojT, W1T, W2T,
                                           bqkv, wkmT, bkm);
    // 2. QKV GEMM -> qk bf16 + V^T
    gemm192<<<dim3(3 * D_ / BN2, B_ * L_ / BM2, 1), 512, 0, stream>>>(
        h_bf16, WqkvT, bqkv, qkb, vtb, B_ * L_, 3 * D_, D_, 4);
    // 3-4. merge decision path
    kmerge_kn<<<B_ * L_ / 16, 256, 0, stream>>>(h_f32, wkmT, bkm, aset, bset);
    tome_scores<<<dim3(256, B_), 256, 0, stream>>>(aset, bset, nmax, nidx);
    // 5. attention (384 blocks) + sort (2 blocks) in one dispatch
    attn_mfma<<<386, 512, 0, stream>>>(qkb, vtb, ts, ctx, nmax, nidx, src_idx, dst_idx, unm_idx);
    // 6. proj GEMM: split-K=3 -> bf16 partials (reduce fused into merges)
    gemm192<<<dim3(D_ / BN2, B_ * L_ / BM2, 3), 512, 0, stream>>>(
        ctx, WprojT, nullptr, ppartsB, nullptr, B_ * L_, D_, D_, 0);
    // 7-9. token merge + LN2
    merge_init<<<B_ * LN_, 256, 0, stream>>>(ppartsB, bproj, x, ts, unm_idx, x_new, s_new);
    merge_scatter<<<B_ * 512, 256, 0, stream>>>(ppartsB, bproj, x, ts, src_idx, dst_idx, x_new, s_new);
    ln_div_kernel<<<B_ * LN_, 256, 0, stream>>>(x_new, s_new, ln2g, ln2b, h2);
    // 10. MLP1 GEMM + gelu
    gemm192<<<dim3(HID_ / BN2, B_ * LN_ / BM2, 1), 512, 0, stream>>>(
        h2, W1T, b1, mid, nullptr, B_ * LN_, HID_, D_, 1);
    // 11. MLP2 GEMM: split-K=4 -> bf16 partials
    gemm192<<<dim3(D_ / BN2, B_ * LN_ / BM2, 4), 512, 0, stream>>>(
        mid, W2T, nullptr, m2partsB, nullptr, B_ * LN_, D_, HID_, 0);
    // 12. final reduce (+b2 +x_new) -> out
    reduce_splitk<<<(B_ * LN_ * D_ / 4 + 255) / 256, 256, 0, stream>>>(
        m2partsB, b2, x_new, out, 4, B_ * LN_ * D_, D_ / 4, B_ * LN_ * D_ / 4);
}

// Round 16
// 237.504 us; speedup vs baseline: 1.2203x; 1.2203x over previous
//
#include <hip/hip_runtime.h>
#include <hip/hip_bf16.h>

typedef __attribute__((ext_vector_type(4))) float f32x4;
typedef __attribute__((ext_vector_type(8))) short s16x8;
typedef unsigned short u16;

#define B_   2
#define L_   2048
#define D_   768
#define H_   12
#define HD_  64
#define LN_  1536   // merged length: 512 unm + 1024 dst
#define HID_ 3072

__device__ __forceinline__ u16 f2bf(float f) {
    union { float f; unsigned u; } v; v.f = f;
    unsigned r = (v.u + 0x7FFFu + ((v.u >> 16) & 1u)) >> 16;
    return (u16)r;
}
__device__ __forceinline__ float bf2f(u16 v) {
    union { unsigned u; float f; } x; x.u = ((unsigned)v) << 16; return x.f;
}

__device__ __forceinline__ void gload_lds16(const void* g, void* l) {
    __builtin_amdgcn_global_load_lds((const __attribute__((address_space(1))) void*)g,
                                     (__attribute__((address_space(3))) void*)l, 16, 0, 0);
}

#define WAITV(n) asm volatile("s_waitcnt vmcnt(" #n ")" ::: "memory")

// ======= fused setup: LN1 (blocks 0..4095) | weight transposes (4096..11007) | wkm (11008..11199) =======
__global__ __launch_bounds__(256) void setup_fused(const float* __restrict__ x,
                                                   const float* __restrict__ ln1g,
                                                   const float* __restrict__ ln1b,
                                                   float* __restrict__ hf,
                                                   u16* __restrict__ hb,
                                                   const float* __restrict__ Wqkv,
                                                   const float* __restrict__ Wproj,
                                                   const float* __restrict__ W1,
                                                   const float* __restrict__ W2,
                                                   u16* __restrict__ WqkvT, u16* __restrict__ WprojT,
                                                   u16* __restrict__ W1T, u16* __restrict__ W2T,
                                                   const float* __restrict__ bqkv,
                                                   float* __restrict__ wkmT, float* __restrict__ bkm) {
    __shared__ float sm[8];
    __shared__ float tile[32][33];
    int bid = blockIdx.x;
    int t = threadIdx.x;
    if (bid < 4096) {
        int row = bid;
        const float* xr = x + (size_t)row * D_;
        float4 v = make_float4(0.f, 0.f, 0.f, 0.f);
        float s = 0.f, s2 = 0.f;
        if (t < 192) {
            v = ((const float4*)xr)[t];
            s = v.x + v.y + v.z + v.w;
            s2 = v.x * v.x + v.y * v.y + v.z * v.z + v.w * v.w;
        }
        for (int o = 32; o; o >>= 1) { s += __shfl_down(s, o); s2 += __shfl_down(s2, o); }
        int wv = t >> 6, ln = t & 63;
        if (ln == 0) { sm[wv] = s; sm[4 + wv] = s2; }
        __syncthreads();
        if (t == 0) { sm[0] = sm[0] + sm[1] + sm[2] + sm[3]; sm[4] = sm[4] + sm[5] + sm[6] + sm[7]; }
        __syncthreads();
        float mu = sm[0] * (1.f / D_);
        float var = sm[4] * (1.f / D_) - mu * mu;
        float rs = rsqrtf(var + 1e-5f);
        if (t < 192) {
            float4 gg = ((const float4*)ln1g)[t], bv = ((const float4*)ln1b)[t];
            float4 o;
            o.x = (v.x - mu) * rs * gg.x + bv.x;
            o.y = (v.y - mu) * rs * gg.y + bv.y;
            o.z = (v.z - mu) * rs * gg.z + bv.z;
            o.w = (v.w - mu) * rs * gg.w + bv.w;
            ((float4*)(hf + (size_t)row * D_))[t] = o;
            ushort4 u;
            u.x = f2bf(o.x); u.y = f2bf(o.y); u.z = f2bf(o.z); u.w = f2bf(o.w);
            ((ushort4*)(hb + (size_t)row * D_))[t] = u;
        }
        return;
    }
    if (bid < 11008) {
        int lb = bid - 4096;
        const float* in; u16* out; int R, C, gx, local;
        if (lb < 1728)      { in = Wqkv;  out = WqkvT;  R = D_;   C = 3 * D_; gx = 72; local = lb; }
        else if (lb < 2304) { in = Wproj; out = WprojT; R = D_;   C = D_;     gx = 24; local = lb - 1728; }
        else if (lb < 4608) { in = W1;    out = W1T;    R = D_;   C = HID_;   gx = 96; local = lb - 2304; }
        else                { in = W2;    out = W2T;    R = HID_; C = D_;     gx = 24; local = lb - 4608; }
        int c0 = (local % gx) * 32, r0 = (local / gx) * 32;
        int tx = t & 31, ty = t >> 5;   // 32 x 8
        for (int i = 0; i < 32; i += 8)
            tile[ty + i][tx] = in[(size_t)(r0 + ty + i) * C + c0 + tx];
        __syncthreads();
        for (int i = 0; i < 32; i += 8)
            out[(size_t)(c0 + ty + i) * R + r0 + tx] = f2bf(tile[tx][ty + i]);
        return;
    }
    {
        int idx = (bid - 11008) * 256 + t;
        if (idx < D_ * HD_) {
            int k = idx >> 6, c = idx & 63;
            float s = 0.f;
            #pragma unroll
            for (int hh = 0; hh < H_; ++hh) s += Wqkv[(size_t)k * (3 * D_) + D_ + hh * HD_ + c];
            wkmT[(size_t)c * D_ + k] = s * (1.f / H_);
        }
        if (idx < HD_) {
            float s = 0.f;
            #pragma unroll
            for (int hh = 0; hh < H_; ++hh) s += bqkv[D_ + hh * HD_ + idx];
            bkm[idx] = s * (1.f / H_);
        }
    }
}

// ---------------- fused merge_div + LayerNorm2 ----------------
__global__ __launch_bounds__(256) void ln_div_kernel(float* __restrict__ x_new,
                                                     const float* __restrict__ s_new,
                                                     const float* __restrict__ g,
                                                     const float* __restrict__ bb,
                                                     u16* __restrict__ hb) {
    __shared__ float sm[8];
    int row = blockIdx.x;
    float inv = 1.f / (s_new[row] + 1e-8f);
    float* xr = x_new + (size_t)row * D_;
    int t = threadIdx.x;
    float4 v = make_float4(0.f, 0.f, 0.f, 0.f);
    float s = 0.f, s2 = 0.f;
    if (t < 192) {
        v = ((float4*)xr)[t];
        v.x *= inv; v.y *= inv; v.z *= inv; v.w *= inv;
        ((float4*)xr)[t] = v;
        s = v.x + v.y + v.z + v.w;
        s2 = v.x * v.x + v.y * v.y + v.z * v.z + v.w * v.w;
    }
    for (int o = 32; o; o >>= 1) { s += __shfl_down(s, o); s2 += __shfl_down(s2, o); }
    int wv = t >> 6, ln = t & 63;
    if (ln == 0) { sm[wv] = s; sm[4 + wv] = s2; }
    __syncthreads();
    if (t == 0) { sm[0] = sm[0] + sm[1] + sm[2] + sm[3]; sm[4] = sm[4] + sm[5] + sm[6] + sm[7]; }
    __syncthreads();
    float mu = sm[0] * (1.f / D_);
    float var = sm[4] * (1.f / D_) - mu * mu;
    float rs = rsqrtf(var + 1e-5f);
    if (t < 192) {
        float4 gg = ((const float4*)g)[t], bv = ((const float4*)bb)[t];
        ushort4 u;
        u.x = f2bf((v.x - mu) * rs * gg.x + bv.x);
        u.y = f2bf((v.y - mu) * rs * gg.y + bv.y);
        u.z = f2bf((v.z - mu) * rs * gg.z + bv.z);
        u.w = f2bf((v.w - mu) * rs * gg.w + bv.w);
        ((ushort4*)(hb + (size_t)row * D_))[t] = u;
    }
}

// ---------------- split-K bf16 partial reduce: out = sum(parts) + bias + resid ----------------
__global__ __launch_bounds__(256) void reduce_splitk(const u16* __restrict__ parts,
                                                     const float* __restrict__ bias,
                                                     const float* __restrict__ resid,
                                                     float* __restrict__ out,
                                                     int nparts, int MN, int N4, int total4) {
    int i = blockIdx.x * 256 + threadIdx.x;
    if (i >= total4) return;
    float4 s = ((const float4*)bias)[i % N4];
    if (resid) {
        float4 r = ((const float4*)resid)[i];
        s.x += r.x; s.y += r.y; s.z += r.z; s.w += r.w;
    }
    for (int p = 0; p < nparts; ++p) {
        ushort4 v = *(const ushort4*)(parts + (size_t)p * MN + 4 * (size_t)i);
        s.x += bf2f(v.x); s.y += bf2f(v.y); s.z += bf2f(v.z); s.w += bf2f(v.w);
    }
    ((float4*)out)[i] = s;
}

// ========== unified 128x192 GEMM, 512 thr / 8 waves, 2 blocks/CU (r12 config) ==========
#define BM2 128
#define BN2 192
#define BK2 64
__global__ __launch_bounds__(512, 4) void gemm192(const u16* __restrict__ A, const u16* __restrict__ BT,
                                                  const float* __restrict__ bias,
                                                  u16* __restrict__ Cb,
                                                  u16* __restrict__ Vt,
                                                  int M, int N, int K, int flags) {
    __shared__ __align__(16) u16 As[2][BM2 * BK2];   // 32 KiB
    __shared__ __align__(16) u16 Bs[2][BN2 * BK2];   // 48 KiB
    int tid = threadIdx.x;
    int wave = tid >> 6, lane = tid & 63;
    int wr = wave >> 2, wc = wave & 3;
    int l15 = lane & 15, l4 = lane >> 4;
    int mBase = blockIdx.y * BM2, nBase = blockIdx.x * BN2;
    f32x4 acc[4][3] = {};
    int Ksplit = K / gridDim.z;
    int kt0 = (blockIdx.z * Ksplit) / BK2, kt1 = kt0 + Ksplit / BK2;
    int lrow = lane >> 3, lsl = lane & 7;

    auto stage = [&](int kt, int buf) {   // 5 loads/thread (2 A + 3 B)
        size_t koff = (size_t)kt * BK2;
        #pragma unroll
        for (int i = 0; i < 2; ++i) {
            int rbase = wave * 16 + i * 8;
            int row = rbase + lrow;
            int gc = lsl ^ (row & 7);
            gload_lds16(A + (size_t)(mBase + row) * K + koff + gc * 8, &As[buf][rbase * BK2]);
        }
        #pragma unroll
        for (int i = 0; i < 3; ++i) {
            int rbase = wave * 24 + i * 8;
            int row = rbase + lrow;
            int gc = lsl ^ (row & 7);
            gload_lds16(BT + (size_t)(nBase + row) * K + koff + gc * 8, &Bs[buf][rbase * BK2]);
        }
    };

    stage(kt0, 0);
    int cur = 0;
    for (int kt = kt0; kt < kt1; ++kt) {
        if (kt + 1 < kt1) {
            stage(kt + 1, cur ^ 1);
            WAITV(5);
        } else {
            WAITV(0);
        }
        __builtin_amdgcn_s_barrier();
        #pragma unroll
        for (int kk = 0; kk < 2; ++kk) {
            s16x8 af[4], bf[3];
            #pragma unroll
            for (int mi = 0; mi < 4; ++mi) {
                int row = wr * 64 + mi * 16 + l15;
                int ch = kk * 4 + l4;
                af[mi] = *(const s16x8*)&As[cur][row * BK2 + ((ch ^ (row & 7)) * 8)];
            }
            #pragma unroll
            for (int ni = 0; ni < 3; ++ni) {
                int row = wc * 48 + ni * 16 + l15;
                int ch = kk * 4 + l4;
                bf[ni] = *(const s16x8*)&Bs[cur][row * BK2 + ((ch ^ (row & 7)) * 8)];
            }
            __builtin_amdgcn_s_setprio(1);
            #pragma unroll
            for (int mi = 0; mi < 4; ++mi)
                #pragma unroll
                for (int ni = 0; ni < 3; ++ni)
                    acc[mi][ni] = __builtin_amdgcn_mfma_f32_16x16x32_bf16(af[mi], bf[ni], acc[mi][ni], 0, 0, 0);
            __builtin_amdgcn_s_setprio(0);
        }
        asm volatile("s_waitcnt lgkmcnt(0)" ::: "memory");
        __builtin_amdgcn_s_barrier();
        cur ^= 1;
    }

    if (flags & 4) {
        #pragma unroll
        for (int mi = 0; mi < 4; ++mi) {
            int r0 = mBase + wr * 64 + mi * 16 + l4 * 4;
            #pragma unroll
            for (int ni = 0; ni < 3; ++ni) {
                int c0 = nBase + wc * 48 + ni * 16;
                int col = c0 + l15;
                float bv = bias[col];
                if (c0 < 1536) {
                    #pragma unroll
                    for (int j = 0; j < 4; ++j)
                        Cb[(size_t)(r0 + j) * 1536 + col] = f2bf(acc[mi][ni][j] + bv);
                } else {
                    int hh = (col - 1536) >> 6, dd = (col - 1536) & 63;
                    int bb2 = r0 >> 11, tok = r0 & 2047;
                    ushort4 u;
                    u.x = f2bf(acc[mi][ni][0] + bv);
                    u.y = f2bf(acc[mi][ni][1] + bv);
                    u.z = f2bf(acc[mi][ni][2] + bv);
                    u.w = f2bf(acc[mi][ni][3] + bv);
                    *(ushort4*)&Vt[(((size_t)bb2 * H_ + hh) * HD_ + dd) * (size_t)L_ + tok] = u;
                }
            }
        }
        return;
    }
    if (gridDim.z > 1) {
        u16* dst = Cb + (size_t)blockIdx.z * M * N;
        #pragma unroll
        for (int mi = 0; mi < 4; ++mi)
            #pragma unroll
            for (int j = 0; j < 4; ++j) {
                int row = mBase + wr * 64 + mi * 16 + l4 * 4 + j;
                #pragma unroll
                for (int ni = 0; ni < 3; ++ni) {
                    int col = nBase + wc * 48 + ni * 16 + l15;
                    dst[(size_t)row * N + col] = f2bf(acc[mi][ni][j]);
                }
            }
        return;
    }
    #pragma unroll
    for (int mi = 0; mi < 4; ++mi) {
        #pragma unroll
        for (int j = 0; j < 4; ++j) {
            int row = mBase + wr * 64 + mi * 16 + l4 * 4 + j;
            #pragma unroll
            for (int ni = 0; ni < 3; ++ni) {
                int col = nBase + wc * 48 + ni * 16 + l15;
                float v = acc[mi][ni][j] + bias[col];
                if (flags & 1) v = 0.5f * v * (1.f + erff(v * 0.70710678118654752f));
                Cb[(size_t)row * N + col] = f2bf(v);
            }
        }
    }
}

// ---------------- k_merge + normalize + even/odd split (fp32) v2 ----------------
__global__ __launch_bounds__(256) void kmerge_kn(const float* __restrict__ hf, const float* __restrict__ wkmT,
                                                 const float* __restrict__ bkm,
                                                 float* __restrict__ aset, float* __restrict__ bset) {
    __shared__ __align__(16) float hfs[16][768];   // 48 KB
    int t = threadIdx.x, wave = t >> 6, lane = t & 63;
    int m0 = blockIdx.x * 16;
    for (int i = t; i < 16 * 192; i += 256) {
        int r = i / 192, c = i % 192;
        ((float4*)hfs[r])[c] = ((const float4*)(hf + (size_t)(m0 + r) * D_))[c];
    }
    __syncthreads();
    int r0 = wave * 4;
    float acc0 = 0.f, acc1 = 0.f, acc2 = 0.f, acc3 = 0.f;
    const float4* wrow = (const float4*)(wkmT + (size_t)lane * D_);
    #pragma unroll 4
    for (int k4 = 0; k4 < 192; ++k4) {
        float4 w = wrow[k4];
        float4 h0 = ((const float4*)hfs[r0 + 0])[k4];
        float4 h1 = ((const float4*)hfs[r0 + 1])[k4];
        float4 h2 = ((const float4*)hfs[r0 + 2])[k4];
        float4 h3 = ((const float4*)hfs[r0 + 3])[k4];
        acc0 = fmaf(h0.x, w.x, acc0); acc0 = fmaf(h0.y, w.y, acc0);
        acc0 = fmaf(h0.z, w.z, acc0); acc0 = fmaf(h0.w, w.w, acc0);
        acc1 = fmaf(h1.x, w.x, acc1); acc1 = fmaf(h1.y, w.y, acc1);
        acc1 = fmaf(h1.z, w.z, acc1); acc1 = fmaf(h1.w, w.w, acc1);
        acc2 = fmaf(h2.x, w.x, acc2); acc2 = fmaf(h2.y, w.y, acc2);
        acc2 = fmaf(h2.z, w.z, acc2); acc2 = fmaf(h2.w, w.w, acc2);
        acc3 = fmaf(h3.x, w.x, acc3); acc3 = fmaf(h3.y, w.y, acc3);
        acc3 = fmaf(h3.z, w.z, acc3); acc3 = fmaf(h3.w, w.w, acc3);
    }
    float accs[4] = {acc0, acc1, acc2, acc3};
    #pragma unroll
    for (int r = 0; r < 4; ++r) {
        float v = accs[r] + bkm[lane];
        float n2 = v * v;
        for (int o = 32; o; o >>= 1) n2 += __shfl_xor(n2, o);
        float kn = v / (sqrtf(n2) + 1e-8f);
        int m = m0 + r0 + r;
        int bb = m >> 11, l = m & 2047;
        float* dp = (l & 1) ? bset : aset;
        dp[((size_t)bb * 1024 + (l >> 1)) * 64 + lane] = kn;
    }
}

// ---------------- ToMe scores: rowwise max+argmax over 1024 cols ----------------
__global__ __launch_bounds__(256) void tome_scores(const float* __restrict__ aset, const float* __restrict__ bset,
                                                   float* __restrict__ node_max, int* __restrict__ node_idx) {
    __shared__ float aves[4][64];
    __shared__ unsigned long long wmax[4][4];
    int b = blockIdx.y;
    int a0 = blockIdx.x * 4;
    int t = threadIdx.x;
    { int r = t >> 6, d = t & 63; aves[r][d] = aset[((size_t)b * 1024 + a0 + r) * 64 + d]; }
    __syncthreads();
    unsigned long long best[4] = {0ull, 0ull, 0ull, 0ull};
    for (int c = t; c < 1024; c += 256) {
        const float4* brow = (const float4*)(bset + ((size_t)b * 1024 + c) * 64);
        float dot[4] = {0.f, 0.f, 0.f, 0.f};
        #pragma unroll
        for (int i = 0; i < 16; ++i) {
            float4 bv = brow[i];
            #pragma unroll
            for (int r = 0; r < 4; ++r) {
                dot[r] = fmaf(aves[r][4 * i + 0], bv.x, dot[r]);
                dot[r] = fmaf(aves[r][4 * i + 1], bv.y, dot[r]);
                dot[r] = fmaf(aves[r][4 * i + 2], bv.z, dot[r]);
                dot[r] = fmaf(aves[r][4 * i + 3], bv.w, dot[r]);
            }
        }
        #pragma unroll
        for (int r = 0; r < 4; ++r) {
            unsigned bits = __float_as_uint(dot[r]);
            unsigned u = (bits & 0x80000000u) ? ~bits : (bits | 0x80000000u);
            unsigned long long key = ((unsigned long long)u << 32) | (unsigned)(0xFFFFFFFFu - (unsigned)c);
            best[r] = best[r] > key ? best[r] : key;
        }
    }
    int wv = t >> 6, ln = t & 63;
    #pragma unroll
    for (int r = 0; r < 4; ++r) {
        unsigned long long v = best[r];
        for (int o = 32; o; o >>= 1) {
            unsigned long long w = __shfl_xor(v, o);
            v = v > w ? v : w;
        }
        if (ln == 0) wmax[r][wv] = v;
    }
    __syncthreads();
    if (t == 0) {
        for (int r = 0; r < 4; ++r) {
            int a = a0 + r;
            unsigned long long m = wmax[r][0];
            for (int w = 1; w < 4; ++w) m = m > wmax[r][w] ? m : wmax[r][w];
            float val; int idx;
            if (a == 0) { val = -INFINITY; idx = 0; }
            else {
                unsigned u = (unsigned)(m >> 32);
                unsigned bits = (u & 0x80000000u) ? (u ^ 0x80000000u) : ~u;
                val = __uint_as_float(bits);
                idx = (int)(0xFFFFFFFFu - (unsigned)(m & 0xFFFFFFFFu));
            }
            node_max[b * 1024 + a] = val;
            node_idx[b * 1024 + a] = idx;
        }
    }
}

// ---------------- exact rank-select argsort (keys unique) ----------------
__global__ __launch_bounds__(1024) void tome_sort(const float* __restrict__ node_max, const int* __restrict__ node_idx,
                                                  int* __restrict__ src_idx, int* __restrict__ dst_idx,
                                                  int* __restrict__ unm_idx) {
    __shared__ unsigned long long keys[1024];
    __shared__ int wcnt[16];
    int b = blockIdx.x, t = threadIdx.x;
    int wv = t >> 6, lane = t & 63;
    float v = node_max[b * 1024 + t];
    unsigned bits = __float_as_uint(v);
    unsigned u = (bits & 0x80000000u) ? ~bits : (bits | 0x80000000u);
    unsigned long long key = ((unsigned long long)(~u) << 32) | (unsigned)t;
    keys[t] = key;
    __syncthreads();
    int rank = 0;
    #pragma unroll 8
    for (int j = 0; j < 1024; ++j) rank += (keys[j] < key) ? 1 : 0;
    if (rank < 512) {
        src_idx[b * 512 + rank] = t;
        dst_idx[b * 512 + rank] = node_idx[b * 1024 + t];
    }
    bool tail = (rank >= 512);
    unsigned long long m = __ballot(tail);
    int lanePfx = __popcll(m & ((1ull << lane) - 1ull));
    if (lane == 0) wcnt[wv] = __popcll(m);
    __syncthreads();
    if (tail) {
        int off = 0;
        #pragma unroll
        for (int w = 0; w < 16; ++w) off += (w < wv) ? wcnt[w] : 0;
        unm_idx[b * 512 + off + lanePfx] = t;
    }
}

// ---------------- windowed attention via MFMA: 128 queries/block, 8 waves (r14 version) ----------------
__global__ __launch_bounds__(512) void attn_mfma(const u16* __restrict__ qkb,
                                                 const u16* __restrict__ vtb,
                                                 const float* __restrict__ ts,
                                                 u16* __restrict__ ctx) {
    __shared__ __align__(16) u16 Ks[192 * 64];      // 24 KB
    __shared__ __align__(16) u16 Vt[64][200];       // 25.6 KB
    __shared__ float lts[192];
    __shared__ __align__(16) u16 Pw[8][16 * 40];    // 10 KB
    int qt = blockIdx.x, h = blockIdx.y, b = blockIdx.z;
    int tid = threadIdx.x, wave = tid >> 6, lane = tid & 63;
    int l15 = lane & 15, l4 = lane >> 4;
    int qbase = qt * 128 + wave * 16;
    int jbase0 = qt * 128 - 128;

    s16x8 qaf[2];
    {
        const u16* qp = qkb + (size_t)(b * L_ + qbase + l15) * 1536 + h * HD_;
        qaf[0] = *(const s16x8*)(qp + l4 * 8);
        qaf[1] = *(const s16x8*)(qp + 32 + l4 * 8);
    }
    f32x4 oacc[4] = {};
    float sums[4] = {0.f, 0.f, 0.f, 0.f};
    const u16* vbase = vtb + (size_t)(b * H_ + h) * HD_ * L_;

    for (int half = 0; half < 2; ++half) {
        int jbase = jbase0 + half * 192;
        __syncthreads();
        #pragma unroll
        for (int i = 0; i < 3; ++i) {
            int rbase = (wave * 3 + i) * 8;
            int row = rbase + (lane >> 3);
            int gc = (lane & 7) ^ (row & 7);
            int jc = min(max(jbase + row, 0), L_ - 1);
            gload_lds16(qkb + (size_t)(b * L_ + jc) * 1536 + 768 + h * HD_ + gc * 8, &Ks[rbase * 64]);
        }
        #pragma unroll
        for (int i = 0; i < 3; ++i) {
            int c = tid + 512 * i;          // 0..1535
            int d = c / 24, ch = c % 24;
            int tok0 = min(max(jbase + ch * 8, 0), L_ - 8);
            s16x8 v = *(const s16x8*)(vbase + (size_t)d * L_ + tok0);
            *(s16x8*)&Vt[d][ch * 8] = v;
        }
        if (tid < 192) {
            int jc = min(max(jbase + tid, 0), L_ - 1);
            lts[tid] = __logf(fmaxf(ts[b * L_ + jc], 1e-8f));
        }
        __syncthreads();
        #pragma unroll
        for (int kb = 0; kb < 6; ++kb) {
            #pragma unroll
            for (int f = 0; f < 2; ++f) {
                int kf16 = kb * 32 + f * 16;
                f32x4 s = {};
                #pragma unroll
                for (int c = 0; c < 2; ++c) {
                    int row = kf16 + l15;
                    int ch = (c * 4 + l4) ^ (row & 7);
                    s16x8 kf = *(const s16x8*)&Ks[row * 64 + ch * 8];
                    s = __builtin_amdgcn_mfma_f32_16x16x32_bf16(qaf[c], kf, s, 0, 0, 0);
                }
                int j = jbase + kf16 + l15;
                float lt = lts[kf16 + l15];
                #pragma unroll
                for (int jj = 0; jj < 4; ++jj) {
                    int q = qbase + l4 * 4 + jj;
                    int d = j - q;
                    bool ok = (j >= 0) && (j < L_) && (d >= -128) && (d <= 128);
                    float p = ok ? __expf(s[jj] * 0.125f + lt) : 0.f;
                    sums[jj] += p;
                    Pw[wave][(l4 * 4 + jj) * 40 + f * 16 + l15] = f2bf(p);
                }
            }
            asm volatile("s_waitcnt lgkmcnt(0)" ::: "memory");
            s16x8 paf = *(const s16x8*)&Pw[wave][l15 * 40 + l4 * 8];
            #pragma unroll
            for (int df = 0; df < 4; ++df) {
                s16x8 vbf = *(const s16x8*)&Vt[df * 16 + l15][kb * 32 + l4 * 8];
                oacc[df] = __builtin_amdgcn_mfma_f32_16x16x32_bf16(paf, vbf, oacc[df], 0, 0, 0);
            }
        }
    }
    #pragma unroll
    for (int jj = 0; jj < 4; ++jj) {
        float s = sums[jj];
        s += __shfl_xor(s, 1); s += __shfl_xor(s, 2);
        s += __shfl_xor(s, 4); s += __shfl_xor(s, 8);
        sums[jj] = 1.f / s;
    }
    #pragma unroll
    for (int jj = 0; jj < 4; ++jj) {
        int q = qbase + l4 * 4 + jj;
        u16* crow = ctx + (size_t)(b * L_ + q) * D_ + h * HD_;
        #pragma unroll
        for (int df = 0; df < 4; ++df)
            crow[df * 16 + l15] = f2bf(oacc[df][jj] * sums[jj]);
    }
}

// ---------------- merge kernels (fused proj split-K=3 bf16-partial reduce) ----------------
#define PMN (B_ * L_ * D_)   // one proj partial in elements

__device__ __forceinline__ float4 proj_row4(const u16* __restrict__ pp,
                                            const float* __restrict__ bproj,
                                            const float* __restrict__ x,
                                            int tok /*0..B*L-1*/, int t /*0..191*/) {
    size_t base = (size_t)tok * D_ + 4 * t;
    float4 s = ((const float4*)bproj)[t];
    float4 xv = ((const float4*)(x + (size_t)tok * D_))[t];
    s.x += xv.x; s.y += xv.y; s.z += xv.z; s.w += xv.w;
    #pragma unroll
    for (int p = 0; p < 3; ++p) {
        ushort4 v = *(const ushort4*)(pp + (size_t)p * PMN + base);
        s.x += bf2f(v.x); s.y += bf2f(v.y); s.z += bf2f(v.z); s.w += bf2f(v.w);
    }
    return s;
}

__global__ __launch_bounds__(256) void merge_init(const u16* __restrict__ pp,
                                                  const float* __restrict__ bproj,
                                                  const float* __restrict__ x,
                                                  const float* __restrict__ ts,
                                                  const int* __restrict__ unm_idx,
                                                  float* __restrict__ x_sum, float* __restrict__ s_new) {
    int row = blockIdx.x;
    int b = row / LN_, rl = row % LN_;
    int srcTok = (rl < 512) ? (2 * unm_idx[b * 512 + rl]) : (2 * (rl - 512) + 1);
    float tsv = ts[b * L_ + srcTok];
    int t = threadIdx.x;
    if (t < 192) {
        float4 v = proj_row4(pp, bproj, x, b * L_ + srcTok, t);
        v.x *= tsv; v.y *= tsv; v.z *= tsv; v.w *= tsv;
        ((float4*)(x_sum + (size_t)(b * LN_ + rl) * D_))[t] = v;
    }
    if (t == 0) s_new[b * LN_ + rl] = tsv;
}

__global__ __launch_bounds__(256) void merge_scatter(const u16* __restrict__ pp,
                                                     const float* __restrict__ bproj,
                                                     const float* __restrict__ x,
                                                     const float* __restrict__ ts,
                                                     const int* __restrict__ src_idx, const int* __restrict__ dst_idx,
                                                     float* __restrict__ x_sum, float* __restrict__ s_new) {
    int e = blockIdx.x;
    int b = e >> 9, el = e & 511;
    int s = src_idx[b * 512 + el];
    int dtok = dst_idx[b * 512 + el];
    int srcTok = 2 * s;
    float tsv = ts[b * L_ + srcTok];
    float* dst = x_sum + (size_t)(b * LN_ + 512 + dtok) * D_;
    int t = threadIdx.x;
    if (t < 192) {
        float4 v = proj_row4(pp, bproj, x, b * L_ + srcTok, t);
        atomicAdd(&dst[4 * t + 0], v.x * tsv);
        atomicAdd(&dst[4 * t + 1], v.y * tsv);
        atomicAdd(&dst[4 * t + 2], v.z * tsv);
        atomicAdd(&dst[4 * t + 3], v.w * tsv);
    }
    if (t == 0) atomicAdd(&s_new[b * LN_ + 512 + dtok], tsv);
}

extern "C" void kernel_launch(void* const* d_in, const int* in_sizes, int n_in,
                              void* d_out, int out_size, void* d_ws, size_t ws_size,
                              hipStream_t stream) {
    (void)in_sizes; (void)n_in; (void)out_size; (void)ws_size;
    const float* x     = (const float*)d_in[0];
    const float* ts    = (const float*)d_in[1];
    const float* ln1g  = (const float*)d_in[2];
    const float* ln1b  = (const float*)d_in[3];
    const float* ln2g  = (const float*)d_in[4];
    const float* ln2b  = (const float*)d_in[5];
    const float* Wqkv  = (const float*)d_in[6];
    const float* bqkv  = (const float*)d_in[7];
    const float* Wproj = (const float*)d_in[8];
    const float* bproj = (const float*)d_in[9];
    const float* W1    = (const float*)d_in[10];
    const float* b1    = (const float*)d_in[11];
    const float* W2    = (const float*)d_in[12];
    const float* b2    = (const float*)d_in[13];
    float* out = (float*)d_out;

    char* ws = (char*)d_ws;
    float* h_f32   = (float*)(ws + 0);            // 12582912
    u16*   h_bf16  = (u16*)(ws + 12582912);       // 6291456 (-> ctx)
    u16*   qkb     = (u16*)(ws + 18874368);       // 12582912 (dead after attn)
    u16*   vtb     = (u16*)(ws + 31457280);       // 6291456  (dead after attn)
    u16*   mid     = (u16*)(ws + 37748736);       // 18874368
    float* x_new   = (float*)(ws + 56623104);     // 9437184
    float* s_new   = (float*)(ws + 66060288);     // 12288
    u16*   h2      = (u16*)(ws + 66072576);       // 4718592
    u16*   WqkvT   = (u16*)(ws + 70791168);       // 3538944
    u16*   WprojT  = (u16*)(ws + 74330112);       // 1179648
    u16*   W1T     = (u16*)(ws + 75509760);       // 4718592
    u16*   W2T     = (u16*)(ws + 80228352);       // 4718592
    float* wkmT    = (float*)(ws + 84946944);     // 196608
    float* bkm     = (float*)(ws + 85143552);     // 256
    float* aset    = (float*)(ws + 85143808);     // 524288
    float* bset    = (float*)(ws + 85668096);     // 524288
    float* nmax    = (float*)(ws + 86192384);     // 8192
    int*   nidx    = (int*)(ws + 86200576);       // 8192
    int*   src_idx = (int*)(ws + 86208768);       // 4096
    int*   dst_idx = (int*)(ws + 86212864);       // 4096
    int*   unm_idx = (int*)(ws + 86216960);       // 4096
    u16*   ctx = h_bf16;
    u16*   ppartsB  = (u16*)(ws + 18874368);      // proj bf16 partials: 3 x 6291456 over qkb+vtb
    u16*   m2partsB = (u16*)(ws + 0);             // mlp2 bf16 partials: 4 x 4718592 over h_f32+ctx

    // 1. fused setup: LN1 + 4 weight transposes + wkm
    setup_fused<<<11200, 256, 0, stream>>>(x, ln1g, ln1b, h_f32, h_bf16,
                                           Wqkv, Wproj, W1, W2, WqkvT, WprojT, W1T, W2T,
                                           bqkv, wkmT, bkm);
    // 2. QKV GEMM -> qk bf16 + V^T
    gemm192<<<dim3(3 * D_ / BN2, B_ * L_ / BM2, 1), 512, 0, stream>>>(
        h_bf16, WqkvT, bqkv, qkb, vtb, B_ * L_, 3 * D_, D_, 4);
    // 3-5. merge decision path
    kmerge_kn<<<B_ * L_ / 16, 256, 0, stream>>>(h_f32, wkmT, bkm, aset, bset);
    tome_scores<<<dim3(256, B_), 256, 0, stream>>>(aset, bset, nmax, nidx);
    tome_sort<<<B_, 1024, 0, stream>>>(nmax, nidx, src_idx, dst_idx, unm_idx);
    // 6. attention: 128 queries/block, 16x12x2 = 384 blocks x 512 thr (61 KB LDS, 2/CU)
    attn_mfma<<<dim3(L_ / 128, H_, B_), 512, 0, stream>>>(qkb, vtb, ts, ctx);
    // 7. proj GEMM: split-K=3 -> bf16 partials (reduce fused into merges)
    gemm192<<<dim3(D_ / BN2, B_ * L_ / BM2, 3), 512, 0, stream>>>(
        ctx, WprojT, nullptr, ppartsB, nullptr, B_ * L_, D_, D_, 0);
    // 8-10. token merge + LN2
    merge_init<<<B_ * LN_, 256, 0, stream>>>(ppartsB, bproj, x, ts, unm_idx, x_new, s_new);
    merge_scatter<<<B_ * 512, 256, 0, stream>>>(ppartsB, bproj, x, ts, src_idx, dst_idx, x_new, s_new);
    ln_div_kernel<<<B_ * LN_, 256, 0, stream>>>(x_new, s_new, ln2g, ln2b, h2);
    // 11. MLP1 GEMM + gelu
    gemm192<<<dim3(HID_ / BN2, B_ * LN_ / BM2, 1), 512, 0, stream>>>(
        h2, W1T, b1, mid, nullptr, B_ * LN_, HID_, D_, 1);
    // 12. MLP2 GEMM: split-K=4 -> bf16 partials
    gemm192<<<dim3(D_ / BN2, B_ * LN_ / BM2, 4), 512, 0, stream>>>(
        mid, W2T, nullptr, m2partsB, nullptr, B_ * LN_, D_, HID_, 0);
    // 13. final reduce (+b2 +x_new) -> out
    reduce_splitk<<<(B_ * LN_ * D_ / 4 + 255) / 256, 256, 0, stream>>>(
        m2partsB, b2, x_new, out, 4, B_ * LN_ * D_, D_ / 4, B_ * LN_ * D_ / 4);
}